// Round 8
// baseline (266.970 us; speedup 1.0000x reference)
//
#include <hip/hip_runtime.h>
#include <math.h>

#define N_PTS 2048
#define K_NN  20
#define K_D   10              // per-slice kept depth
#define WTOT  819200          // total weight elements across the 5 tensors
#define NM_REP 8              // pool-accumulator replicas
#define NM_STRIDE 1536        // floats per replica slot (4 batches * 3 * 128)
#define NM_BLK (NM_REP*NM_STRIDE)
#define NBLK 256              // resnet blocks (32 points each)
#define BPB  64               // blocks per batch
#define ROWS 96               // j-rows per block (32 points * 3)
#define LDS_BYTES (2*ROWS*264*2)   // X + Y regions, 101376 B

typedef unsigned short u16;
typedef unsigned int   u32;
typedef _Float16 f16;
using half8   = __attribute__((ext_vector_type(8))) _Float16;
using floatx4 = __attribute__((ext_vector_type(4))) float;

// Weights: split fp16.  w ~= hi + lo/1024, |err| ~ 2^-24 |w|.
__device__ __forceinline__ void split2h(float v, f16& h, f16& l) {
    h = (f16)v;
    l = (f16)((v - (float)h) * 1024.0f);
}

// nd must be bit-identical in phase 1 and phase 2b.
__device__ __forceinline__ float neg_dist(float4 q2, float4 c) {
    return fmaf(q2.x, c.x, fmaf(q2.y, c.y, fmaf(q2.z, c.z, -q2.w))) - c.w;
}

// ---------------------------------------------------------------------------
// prep_kernel = KNN (blocks 0..1023) + weight convert/swizzle (blocks 1024+).
// Also zeroes nm_acc + arrival counters every launch (replay-safe).
// ---------------------------------------------------------------------------
__global__ __launch_bounds__(256) void prep_kernel(
    const float* __restrict__ pts, float* __restrict__ m_out,
    const float* __restrict__ bd0, const float* __restrict__ bW0,
    const float* __restrict__ bd1, const float* __restrict__ bW1,
    const float* __restrict__ bWs, u16* __restrict__ Wswz,
    float* __restrict__ nm_acc)
{
    __shared__ float4 sp[N_PTS];                      // 32 KB (knn branch only)
    if (blockIdx.x >= 1024) {
        int i = (blockIdx.x - 1024) * 256 + threadIdx.x;
        if (i >= WTOT) return;
        if (i < 5*NM_BLK + 32) nm_acc[i] = 0.f;       // replica sums + counters
        float v; int base, K, local;
        if (i < 327680)      { int rel = i;          base = (rel/65536)*65536;            local = rel%65536; K = 256; v = bd0[rel]; }
        else if (i < 491520) { int rel = i - 327680; base = 327680 + (rel/32768)*32768;   local = rel%32768; K = 256; v = bW0[rel]; }
        else if (i < 573440) { int rel = i - 491520; base = 491520 + (rel/16384)*16384;   local = rel%16384; K = 128; v = bd1[rel]; }
        else if (i < 655360) { int rel = i - 573440; base = 573440 + (rel/16384)*16384;   local = rel%16384; K = 128; v = bW1[rel]; }
        else                 { int rel = i - 655360; base = 655360 + (rel/32768)*32768;   local = rel%32768; K = 256; v = bWs[rel]; }
        int m = local / K, k = local % K;
        int NKF = K >> 5;
        int mf = m >> 4, r = m & 15;
        int kf = k >> 5, q = (k >> 3) & 3, ii = k & 7;
        int lane = q*16 + r;
        int dst = base + ((mf*NKF + kf)*64 + lane)*8 + ii;
        f16 h, l; split2h(v, h, l);
        f16* W = (f16*)Wswz;
        W[dst] = h; W[WTOT + dst] = l;
        return;
    }

    // ---- KNN ----
    const int b     = blockIdx.x >> 8;
    const int qbase = (blockIdx.x & 255) << 3;
    const int ql    = threadIdx.x >> 5;
    const int sl    = threadIdx.x & 31;
    const float* pb = pts + (size_t)b * N_PTS * 3;
    for (int i = threadIdx.x; i < N_PTS; i += 256) {
        float x = pb[i*3+0], y = pb[i*3+1], z = pb[i*3+2];
        sp[i] = make_float4(x, y, z, x*x + y*y + z*z);
    }
    __syncthreads();

    const int n = qbase + ql;
    const float4 q = sp[n];
    const float4 q2 = make_float4(2.f*q.x, 2.f*q.y, 2.f*q.z, q.w);

    float t[K_D];
#pragma unroll
    for (int s = 0; s < K_D; ++s) t[s] = -INFINITY;

    for (int j = 0; j < N_PTS/32; ++j) {
        float4 c = sp[j*32 + sl];
        float v = neg_dist(q2, c);
#pragma unroll
        for (int s = 0; s < K_D; ++s) {
            float nx = (s < K_D-1) ? t[s+1] : INFINITY;
            t[s] = fminf(fmaxf(t[s], v), nx);
        }
    }

    float head = t[K_D-1];
    float T = -INFINITY;
#pragma unroll 1
    for (int e = 0; e < K_NN; ++e) {
        float v = head; int w = sl;
#pragma unroll
        for (int off = 1; off < 32; off <<= 1) {
            float vo = __shfl_xor(v, off);
            int   wo = __shfl_xor(w, off);
            bool take = (vo > v) || (vo == v && wo < w);
            v = take ? vo : v;
            w = take ? wo : w;
        }
        T = v;
        if (w == sl) {
#pragma unroll
            for (int s = K_D-1; s > 0; --s) t[s] = t[s-1];
            t[0] = -INFINITY;
            head = t[K_D-1];
        }
    }

    float sx = 0.f, sy = 0.f, sz = 0.f;
    for (int j = 0; j < N_PTS/32; ++j) {
        float4 c = sp[j*32 + sl];
        float v = neg_dist(q2, c);
        if (v >= T) { sx += c.x; sy += c.y; sz += c.z; }
    }
#pragma unroll
    for (int off = 1; off < 32; off <<= 1) {
        sx += __shfl_xor(sx, off);
        sy += __shfl_xor(sy, off);
        sz += __shfl_xor(sz, off);
    }
    if (sl == 0) {
        const float inv = 1.0f / (float)K_NN;
        const int pt = b * N_PTS + n;
        m_out[pt*3+0] = sx * inv;
        m_out[pt*3+1] = sy * inv;
        m_out[pt*3+2] = sz * inv;
    }
}

// ---------------------------------------------------------------------------
// MFMA GEMM cores: COMPILE-TIME kf-range [KF0,KF1) + full unroll so the
// compiler can software-pipeline A-loads (L2, ~200cy) and B ds_reads across
// steps (the old runtime-bound `#pragma unroll 1` loop forbade any hoisting;
// that form was tuned at 12 waves/CU where TLP hid latency — at 2 waves/SIMD
// ILP must do it). Consecutive ranges keep accumulate order (bit-identical).
// ---------------------------------------------------------------------------
template<int MF, int JF, int NK, int KF0, int KF1>
__device__ __forceinline__ void run_gemm_hi(
    const f16* __restrict__ Whi, size_t aoff,
    const f16* Blds, int bstride, int lane,
    floatx4 (&acc)[MF][JF])
{
    const int l15 = lane & 15;
    const int lq8 = (lane >> 4) * 8;
    half8 Aa[MF], Ab[MF];

    auto loada = [&](half8 (&dst)[MF], int kf) {
#pragma unroll
        for (int fm = 0; fm < MF; ++fm)
            dst[fm] = *(const half8*)(Whi + aoff + (size_t)(fm*NK + kf)*512 + (size_t)lane*8);
    };
    auto step = [&](half8 (&af)[MF], int kf) {
        half8 bq[JF];
#pragma unroll
        for (int fj = 0; fj < JF; ++fj)
            bq[fj] = *(const half8*)&Blds[(fj*16 + l15)*bstride + kf*32 + lq8];
#pragma unroll
        for (int fm = 0; fm < MF; ++fm)
#pragma unroll
            for (int fj = 0; fj < JF; ++fj)
                acc[fm][fj] = __builtin_amdgcn_mfma_f32_16x16x32_f16(af[fm], bq[fj], acc[fm][fj], 0, 0, 0);
    };

    loada(Aa, KF0);
#pragma unroll
    for (int kf = KF0; kf < KF1; kf += 2) {
        loada(Ab, kf + 1);
        step(Aa, kf);
        if (kf + 2 < KF1) loada(Aa, kf + 2);
        step(Ab, kf + 1);
    }
}

template<int MF, int JF, int NK, int KF0, int KF1>
__device__ __forceinline__ void run_gemm_split(
    const f16* __restrict__ Whi, const f16* __restrict__ Wlo, size_t aoff,
    const f16* Blds, int bstride, int lane,
    floatx4 (&acc)[MF][JF], floatx4 (&accL)[MF][JF])
{
    const int l15 = lane & 15;
    const int lq8 = (lane >> 4) * 8;
    half8 Aa[2*MF], Ab[2*MF];

    auto loada = [&](half8 (&dst)[2*MF], int kf) {
#pragma unroll
        for (int fm = 0; fm < MF; ++fm) {
            size_t fo = aoff + (size_t)(fm*NK + kf)*512 + (size_t)lane*8;
            dst[fm*2+0] = *(const half8*)(Whi + fo);
            dst[fm*2+1] = *(const half8*)(Wlo + fo);
        }
    };
    auto step = [&](half8 (&af)[2*MF], int kf) {
        half8 bq[JF];
#pragma unroll
        for (int fj = 0; fj < JF; ++fj)
            bq[fj] = *(const half8*)&Blds[(fj*16 + l15)*bstride + kf*32 + lq8];
#pragma unroll
        for (int fm = 0; fm < MF; ++fm)
#pragma unroll
            for (int fj = 0; fj < JF; ++fj) {
                acc[fm][fj]  = __builtin_amdgcn_mfma_f32_16x16x32_f16(af[fm*2+0], bq[fj], acc[fm][fj], 0, 0, 0);
                accL[fm][fj] = __builtin_amdgcn_mfma_f32_16x16x32_f16(af[fm*2+1], bq[fj], accL[fm][fj], 0, 0, 0);
            }
    };

    loada(Aa, KF0);
#pragma unroll
    for (int kf = KF0; kf < KF1; kf += 2) {
        loada(Ab, kf + 1);
        step(Aa, kf);
        if (kf + 2 < KF1) loada(Aa, kf + 2);
        step(Ab, kf + 1);
    }
}

__device__ __forceinline__ uint2 pack_res(floatx4 a, floatx4 aL) {
    u16 hh[4];
#pragma unroll
    for (int r = 0; r < 4; ++r) {
        f16 hv = (f16)(a[r] + aL[r] * (1.0f/1024.0f));
        hh[r] = *(u16*)&hv;
    }
    uint2 pv;
    pv.x = (u32)hh[0] | ((u32)hh[1] << 16);
    pv.y = (u32)hh[2] | ((u32)hh[3] << 16);
    return pv;
}

__device__ __forceinline__ uint2 pack_hi(floatx4 a) {
    u16 hh[4];
#pragma unroll
    for (int r = 0; r < 4; ++r) {
        f16 hv = (f16)a[r];
        hh[r] = *(u16*)&hv;
    }
    uint2 pv;
    pv.x = (u32)hh[0] | ((u32)hh[1] << 16);
    pv.y = (u32)hh[2] | ((u32)hh[3] << 16);
    return pv;
}

// ---------------------------------------------------------------------------
// FUSED resnet, BIG-TILE + 2-D WAVE GRID + WAIT OVERLAP + STATIC-UNROLL GEMMS:
// 256 blocks x 512 thr (4(M) x 2(N) waves), 96 rows, 101 KB LDS, 1 block/CU.
// Sync stays cache-op-free (raw vmcnt(0) + relaxed atomics; __threadfence
// would emit buffer_wbl2/inv and evict the L2-resident weights).
// ---------------------------------------------------------------------------
__global__ __launch_bounds__(512, 2) void resnet_kernel(
    const u16* __restrict__ Wswz,
    const float* __restrict__ pts, const float* __restrict__ m_buf,
    const float* __restrict__ fcW,
    float* __restrict__ nm_acc, int* __restrict__ cnt,
    const float* __restrict__ act_d, const float* __restrict__ fc_c,
    float* __restrict__ out)
{
    extern __shared__ char smem_raw[];
    f16*   X  = (f16*)smem_raw;            // [ROWS*264] x (w256); later h/y2 @136
    f16*   Yd = X + ROWS*264;              // [ROWS*264] d/y (w256) | d1 @136
    float* YC = (float*)Yd;                // [ROWS*132] C floats | Hf | nmT

    const int tid   = threadIdx.x;                  // 0..511
    const int bB    = blockIdx.x / BPB;             // batch (64 blocks/batch)
    const int lane  = tid & 63;
    const int wv    = tid >> 6;                     // 0..7
    const int mwave = wv >> 1;                      // 0..3 (M-grid)
    const int ncol  = wv & 1;                       // 0..1 (N-grid)
    const f16* Whi = (const f16*)Wswz;
    const f16* Wlo = Whi + WTOT;

#pragma unroll 1
    for (int st = 0; st < 5; ++st) {
        const int offD0 = st*65536;
        const int offW0 = 327680 + st*32768;
        const int offD1 = 491520 + st*16384;
        const int offW1 = 573440 + st*16384;
        const int offWs = 655360 + st*32768;

        // ---- stage 0: build x from fcW/pts/m (later stages: own half set)
        if (st == 0) {
            float* Hf = YC;                 // W(768) p(96)@768 m(96)@864
            const int ptbase = blockIdx.x * 32;
            for (int i = tid; i < 768; i += 512) Hf[i] = fcW[i];
            if (tid < 192) Hf[768 + tid] = (tid < 96) ? pts[ptbase*3 + tid]
                                                      : m_buf[ptbase*3 + tid - 96];
            __syncthreads();
#pragma unroll 1
            for (int it = 0; it < 6; ++it) {
                int idx = tid + 512*it;             // 0..3071
                int r = idx >> 5;                   // j-row 0..95
                int cg = idx & 31;
                int l = r / 3, v = r - l*3;
                float pv0[3] = {Hf[768+l*3], Hf[768+l*3+1], Hf[768+l*3+2]};
                float mv0[3] = {Hf[864+l*3], Hf[864+l*3+1], Hf[864+l*3+2]};
                int v1 = (v==2) ? 0 : v+1;
                int v2 = (v==0) ? 2 : v-1;
                float av = mv0[v] - pv0[v];
                float bv = pv0[v];
                float cv = mv0[v1]*pv0[v2] - mv0[v2]*pv0[v1];
                half8 o;
#pragma unroll
                for (int k = 0; k < 8; ++k) {
                    int ch = cg*8 + k;
                    o[k] = (f16)(Hf[ch*3+0]*av + Hf[ch*3+1]*bv + Hf[ch*3+2]*cv);
                }
                *(half8*)&X[r*264 + cg*8] = o;
            }
            __syncthreads();
        }

        // accumulators: gemm1 (d) + carried net = Ws@x + W1@y2
        floatx4 acc1[4][3];
        floatx4 acc4[2][3], accL4[2][3];
#pragma unroll
        for (int a = 0; a < 4; ++a)
#pragma unroll
            for (int b = 0; b < 3; ++b) acc1[a][b] = (floatx4){0,0,0,0};
#pragma unroll
        for (int a = 0; a < 2; ++a)
#pragma unroll
            for (int b = 0; b < 3; ++b) { acc4[a][b] = (floatx4){0,0,0,0}; accL4[a][b] = (floatx4){0,0,0,0}; }

        if (st == 0) {
            // ---- gemm1 full K; store d -> Yd @264; then gemm4a full K ----
            run_gemm_hi<4,3,8,0,8>(Whi, (size_t)offD0 + (size_t)mwave*16384,
                                   X + ncol*48*264, 264, lane, acc1);
#pragma unroll
            for (int fm = 0; fm < 4; ++fm)
#pragma unroll
                for (int fj = 0; fj < 3; ++fj) {
                    int mloc = mwave*64 + fm*16 + (lane>>4)*4;
                    int jl   = ncol*48 + fj*16 + (lane & 15);
                    *(uint2*)&Yd[jl*264 + mloc] = pack_hi(acc1[fm][fj]);
                }
            __syncthreads();
            run_gemm_split<2,3,8,0,8>(Whi, Wlo, (size_t)offWs + (size_t)mwave*8192,
                                      X + ncol*48*264, 264, lane, acc4, accL4);
        } else {
            // ---- EARLY half (own channels, kf 0..3) before the rendezvous
            run_gemm_hi<4,3,8,0,4>(Whi, (size_t)offD0 + (size_t)mwave*16384,
                                   X + ncol*48*264, 264, lane, acc1);
            run_gemm_split<2,3,8,0,4>(Whi, Wlo, (size_t)offWs + (size_t)mwave*8192,
                                      X + ncol*48*264, 264, lane, acc4, accL4);

            // ---- rendezvous: wait for stage st-1 pool of this batch ------
            if (tid == 0) {
                while (__hip_atomic_load(&cnt[(st-1)*4+bB], __ATOMIC_RELAXED, __HIP_MEMORY_SCOPE_AGENT) < BPB)
                    __builtin_amdgcn_s_sleep(1);
            }
            __syncthreads();

            // ---- fill pooled half of X (cg 16..31) -----------------------
            float* nmSp = nm_acc + (size_t)(st-1)*NM_BLK;
            f16* nmT = Yd;                          // Yd dead until d-store
            if (tid < 384) {
                int v = tid >> 7, ch = tid & 127;
                float sum = 0.f;
#pragma unroll
                for (int rep = 0; rep < NM_REP; ++rep)
                    sum += __hip_atomic_load(nmSp + rep*NM_STRIDE + (bB*3+v)*128 + ch,
                                             __ATOMIC_RELAXED, __HIP_MEMORY_SCOPE_AGENT);
                nmT[tid] = (f16)(sum * (1.0f/2048.0f));
            }
            __syncthreads();
#pragma unroll 1
            for (int idx = tid; idx < 1536; idx += 512) {
                int r = idx >> 4;                   // 0..95
                int cg = (idx & 15) + 16;
                int v = r % 3;
                *(half8*)&X[r*264 + cg*8] = *(const half8*)&nmT[v*128 + (cg-16)*8];
            }
            __syncthreads();

            // ---- LATE half (pooled channels, kf 4..7); store d -----------
            run_gemm_hi<4,3,8,4,8>(Whi, (size_t)offD0 + (size_t)mwave*16384,
                                   X + ncol*48*264, 264, lane, acc1);
#pragma unroll
            for (int fm = 0; fm < 4; ++fm)
#pragma unroll
                for (int fj = 0; fj < 3; ++fj) {
                    int mloc = mwave*64 + fm*16 + (lane>>4)*4;
                    int jl   = ncol*48 + fj*16 + (lane & 15);
                    *(uint2*)&Yd[jl*264 + mloc] = pack_hi(acc1[fm][fj]);
                }
            __syncthreads();
            run_gemm_split<2,3,8,4,8>(Whi, Wlo, (size_t)offWs + (size_t)mwave*8192,
                                      X + ncol*48*264, 264, lane, acc4, accL4);
        }

        // ---- relu1: y = vnrelu(x, d), in place in Y (1024 items) ---------
#pragma unroll 1
        for (int it = 0; it < 2; ++it) {
            int idx = tid + 512*it;
            int l = idx >> 5, cg = idx & 31;      // l 0..31, cg 0..31
            half8 xa = *(const half8*)&X[(l*3+0)*264 + cg*8];
            half8 xb = *(const half8*)&X[(l*3+1)*264 + cg*8];
            half8 xc = *(const half8*)&X[(l*3+2)*264 + cg*8];
            half8 da = *(const half8*)&Yd[(l*3+0)*264 + cg*8];
            half8 db = *(const half8*)&Yd[(l*3+1)*264 + cg*8];
            half8 dc = *(const half8*)&Yd[(l*3+2)*264 + cg*8];
            half8 ya, yb, yc;
#pragma unroll
            for (int k = 0; k < 8; ++k) {
                float x0 = (float)xa[k], x1 = (float)xb[k], x2 = (float)xc[k];
                float d0 = (float)da[k], d1 = (float)db[k], d2 = (float)dc[k];
                float dot = x0*d0 + x1*d1 + x2*d2;
                float y0, y1, y2;
                if (dot >= 0.f) { y0 = x0; y1 = x1; y2 = x2; }
                else {
                    float dsq = d0*d0 + d1*d1 + d2*d2 + 1e-8f;
                    float sc = dot / dsq;
                    y0 = x0 - sc*d0; y1 = x1 - sc*d1; y2 = x2 - sc*d2;
                }
                ya[k] = (f16)y0; yb[k] = (f16)y1; yc[k] = (f16)y2;
            }
            *(half8*)&Yd[(l*3+0)*264 + cg*8] = ya;
            *(half8*)&Yd[(l*3+1)*264 + cg*8] = yb;
            *(half8*)&Yd[(l*3+2)*264 + cg*8] = yc;
        }
        __syncthreads();      // all waves past gemm4a (X free) and relu1

        // ---- gemm2: h = W0 @ y (split), h -> X region @136 ---------------
        {
            floatx4 acc[2][3], accL[2][3];
#pragma unroll
            for (int a = 0; a < 2; ++a)
#pragma unroll
                for (int b = 0; b < 3; ++b) { acc[a][b] = (floatx4){0,0,0,0}; accL[a][b] = (floatx4){0,0,0,0}; }
            run_gemm_split<2,3,8,0,8>(Whi, Wlo, (size_t)offW0 + (size_t)mwave*8192,
                                      Yd + ncol*48*264, 264, lane, acc, accL);
#pragma unroll
            for (int fm = 0; fm < 2; ++fm)
#pragma unroll
                for (int fj = 0; fj < 3; ++fj) {
                    int mloc = mwave*32 + fm*16 + (lane>>4)*4;
                    int jl   = ncol*48 + fj*16 + (lane & 15);
                    *(uint2*)&X[jl*136 + mloc] = pack_res(acc[fm][fj], accL[fm][fj]);
                }
        }
        __syncthreads();

        // ---- gemm3: d1 = D1 @ h (hi-only), d1 -> Y @136 ------------------
        {
            floatx4 acc[2][3];
#pragma unroll
            for (int a = 0; a < 2; ++a)
#pragma unroll
                for (int b = 0; b < 3; ++b) acc[a][b] = (floatx4){0,0,0,0};
            run_gemm_hi<2,3,4,0,4>(Whi, (size_t)offD1 + (size_t)mwave*4096,
                                   X + ncol*48*136, 136, lane, acc);
#pragma unroll
            for (int fm = 0; fm < 2; ++fm)
#pragma unroll
                for (int fj = 0; fj < 3; ++fj) {
                    int mloc = mwave*32 + fm*16 + (lane>>4)*4;
                    int jl   = ncol*48 + fj*16 + (lane & 15);
                    *(uint2*)&Yd[jl*136 + mloc] = pack_hi(acc[fm][fj]);
                }
        }
        __syncthreads();

        // ---- relu2: y2 = vnrelu(h, d1), over h in X @136 (512 items) -----
        {
            int l = tid >> 4, cg = tid & 15;      // l 0..31, cg 0..15
            half8 xa = *(const half8*)&X[(l*3+0)*136 + cg*8];
            half8 xb = *(const half8*)&X[(l*3+1)*136 + cg*8];
            half8 xc = *(const half8*)&X[(l*3+2)*136 + cg*8];
            half8 da = *(const half8*)&Yd[(l*3+0)*136 + cg*8];
            half8 db = *(const half8*)&Yd[(l*3+1)*136 + cg*8];
            half8 dc = *(const half8*)&Yd[(l*3+2)*136 + cg*8];
            half8 ya, yb, yc;
#pragma unroll
            for (int k = 0; k < 8; ++k) {
                float x0 = (float)xa[k], x1 = (float)xb[k], x2 = (float)xc[k];
                float d0 = (float)da[k], d1 = (float)db[k], d2 = (float)dc[k];
                float dot = x0*d0 + x1*d1 + x2*d2;
                float y0, y1, y2;
                if (dot >= 0.f) { y0 = x0; y1 = x1; y2 = x2; }
                else {
                    float dsq = d0*d0 + d1*d1 + d2*d2 + 1e-8f;
                    float sc = dot / dsq;
                    y0 = x0 - sc*d0; y1 = x1 - sc*d1; y2 = x2 - sc*d2;
                }
                ya[k] = (f16)y0; yb[k] = (f16)y1; yc[k] = (f16)y2;
            }
            *(half8*)&X[(l*3+0)*136 + cg*8] = ya;   // per-thread-private rows
            *(half8*)&X[(l*3+1)*136 + cg*8] = yb;
            *(half8*)&X[(l*3+2)*136 + cg*8] = yc;
        }
        __syncthreads();

        // ---- gemm4b: acc4 += W1 @ y2 (split), B = X @136 -----------------
        run_gemm_split<2,3,4,0,4>(Whi, Wlo, (size_t)offW1 + (size_t)mwave*4096,
                                  X + ncol*48*136, 136, lane, acc4, accL4);
        __syncthreads();      // X (@136) dead; safe to rewrite X @264

        // ---- epilogue: next-stage x (f16) -> X @264 cg<16; C -> Y --------
#pragma unroll
        for (int fm = 0; fm < 2; ++fm)
#pragma unroll
            for (int fj = 0; fj < 3; ++fj) {
                int mloc = mwave*32 + fm*16 + (lane>>4)*4;
                int jl   = ncol*48 + fj*16 + (lane & 15);
                floatx4 res;
#pragma unroll
                for (int r = 0; r < 4; ++r) res[r] = acc4[fm][fj][r] + accL4[fm][fj][r] * (1.0f/1024.0f);
                *(uint2*)&X[jl*264 + mloc] = pack_res(acc4[fm][fj], accL4[fm][fj]);
                *(floatx4*)&YC[jl*132 + mloc] = res;
            }
        __syncthreads();

        // ---- pool: sum 32 points per (v, ch) -> replica atomics ----------
        const int rsel = (blockIdx.x & (NM_REP-1)) * NM_STRIDE;
        float* nmS = nm_acc + (size_t)st*NM_BLK;
        if (tid < 384) {
            int v = tid >> 7, ch = tid & 127;
            float sum = 0.f;
#pragma unroll 1
            for (int pt = 0; pt < 32; ++pt) sum += YC[(pt*3+v)*132 + ch];
            atomicAdd(nmS + rsel + (bB*3+v)*128 + ch, sum);
        }
        // Producer ordering WITHOUT cache ops: drain this thread's atomics,
        // then barrier (covers the whole block).
        asm volatile("s_waitcnt vmcnt(0)" ::: "memory");
        __syncthreads();
        if (tid == 0)
            __hip_atomic_fetch_add(&cnt[st*4+bB], 1, __ATOMIC_RELAXED, __HIP_MEMORY_SCOPE_AGENT);
        // NOTE: the wait + pooled-fill for the next stage happens INSIDE
        // the next iteration, after its early-half gemms.
    }

    // ---- folded head: blocks 0..3 compute out[b] -------------------------
    if (blockIdx.x < 4) {
        const int b = blockIdx.x;
        if (tid == 0) {
            while (__hip_atomic_load(&cnt[16+b], __ATOMIC_RELAXED, __HIP_MEMORY_SCOPE_AGENT) < BPB)
                __builtin_amdgcn_s_sleep(1);
        }
        __syncthreads();
        float* xs = (float*)smem_raw;               // [128][3]
        float* ys = xs + 384;
        const float* nm4 = nm_acc + (size_t)4*NM_BLK;
        if (tid < 128) {
            int c = tid;
            float s0 = 0.f, s1 = 0.f, s2 = 0.f;
#pragma unroll
            for (int rep = 0; rep < NM_REP; ++rep) {
                s0 += __hip_atomic_load(nm4 + rep*NM_STRIDE + (b*3+0)*128 + c, __ATOMIC_RELAXED, __HIP_MEMORY_SCOPE_AGENT);
                s1 += __hip_atomic_load(nm4 + rep*NM_STRIDE + (b*3+1)*128 + c, __ATOMIC_RELAXED, __HIP_MEMORY_SCOPE_AGENT);
                s2 += __hip_atomic_load(nm4 + rep*NM_STRIDE + (b*3+2)*128 + c, __ATOMIC_RELAXED, __HIP_MEMORY_SCOPE_AGENT);
            }
            xs[c*3+0] = s0 * (1.0f/2048.0f);
            xs[c*3+1] = s1 * (1.0f/2048.0f);
            xs[c*3+2] = s2 * (1.0f/2048.0f);
        }
        __syncthreads();
        if (tid < 128) {
            int c = tid;
            float d0 = 0.f, d1 = 0.f, d2 = 0.f;
            for (int i = 0; i < 128; ++i) {
                float w = act_d[c*128 + i];
                d0 = fmaf(w, xs[i*3+0], d0);
                d1 = fmaf(w, xs[i*3+1], d1);
                d2 = fmaf(w, xs[i*3+2], d2);
            }
            float x0 = xs[c*3+0], x1 = xs[c*3+1], x2 = xs[c*3+2];
            float dot = x0*d0 + x1*d1 + x2*d2;
            float y0, y1, y2;
            if (dot >= 0.f) { y0 = x0; y1 = x1; y2 = x2; }
            else {
                float dsq = d0*d0 + d1*d1 + d2*d2 + 1e-8f;
                float sc = dot / dsq;
                y0 = x0 - sc*d0; y1 = x1 - sc*d1; y2 = x2 - sc*d2;
            }
            ys[c*3+0] = y0; ys[c*3+1] = y1; ys[c*3+2] = y2;
        }
        __syncthreads();
        if (tid < 128) {
            int c = tid;
            float o0 = 0.f, o1 = 0.f, o2 = 0.f;
            for (int i = 0; i < 128; ++i) {
                float w = fc_c[c*128 + i];
                o0 = fmaf(w, ys[i*3+0], o0);
                o1 = fmaf(w, ys[i*3+1], o1);
                o2 = fmaf(w, ys[i*3+2], o2);
            }
            out[b*384 + c*3 + 0] = o0;
            out[b*384 + c*3 + 1] = o1;
            out[b*384 + c*3 + 2] = o2;
        }
    }
}

// ---------------------------------------------------------------------------
extern "C" void kernel_launch(void* const* d_in, const int* in_sizes, int n_in,
                              void* d_out, int out_size, void* d_ws, size_t ws_size,
                              hipStream_t stream)
{
    const float* p      = (const float*)d_in[0];
    const float* fc_pos = (const float*)d_in[1];
    const float* bd0    = (const float*)d_in[2];
    const float* bW0    = (const float*)d_in[3];
    const float* bd1    = (const float*)d_in[4];
    const float* bW1    = (const float*)d_in[5];
    const float* bWs    = (const float*)d_in[6];
    const float* fc_c   = (const float*)d_in[7];
    const float* act_d  = (const float*)d_in[8];
    float* out = (float*)d_out;

    // Workspace layout (16B-aligned)
    char* w = (char*)d_ws;
    float* m_buf  = (float*)w;  w += 98304;                  // knn means
    float* nm_acc = (float*)w;  w += (size_t)5*NM_BLK*4;     // replicated pool sums
    int*   cnt    = (int*)w;    w += 128;                    // arrival counters (zeroed w/ nm)
    u16*   Wswz   = (u16*)w;    w += (size_t)2*WTOT*2;       // swizzled split weights

    static bool attr_set = false;
    if (!attr_set) {
        hipFuncSetAttribute((const void*)resnet_kernel,
                            hipFuncAttributeMaxDynamicSharedMemorySize, LDS_BYTES);
        attr_set = true;
    }

    prep_kernel<<<dim3(1024 + 3200), dim3(256), 0, stream>>>(
        p, m_buf, bd0, bW0, bd1, bW1, bWs, Wswz, nm_acc);

    resnet_kernel<<<dim3(NBLK), dim3(512), LDS_BYTES, stream>>>(
        Wswz, p, m_buf, fc_pos, nm_acc, cnt, act_d, fc_c, out);

    (void)in_sizes; (void)n_in; (void)out_size; (void)ws_size;
}

// Round 9
// 215.776 us; speedup vs baseline: 1.2373x; 1.2373x over previous
//
#include <hip/hip_runtime.h>
#include <math.h>

#define N_PTS 2048
#define K_NN  20
#define K_D   10              // per-slice kept depth
#define WTOT  819200          // total weight elements across the 5 tensors
#define NM_REP 8              // pool-accumulator replicas
#define NM_STRIDE 1536        // floats per replica slot (4 batches * 3 * 128)
#define NM_BLK (NM_REP*NM_STRIDE)
#define NBLK 256              // resnet blocks (32 points each)
#define BPB  64               // blocks per batch
#define ROWS 96               // j-rows per block (32 points * 3)
#define LDS_BYTES (2*ROWS*264*2)   // X + Y regions, 101376 B

typedef unsigned short u16;
typedef unsigned int   u32;
typedef _Float16 f16;
using half8   = __attribute__((ext_vector_type(8))) _Float16;
using floatx4 = __attribute__((ext_vector_type(4))) float;

// Weights: split fp16.  w ~= hi + lo/1024, |err| ~ 2^-24 |w|.
__device__ __forceinline__ void split2h(float v, f16& h, f16& l) {
    h = (f16)v;
    l = (f16)((v - (float)h) * 1024.0f);
}

// nd must be bit-identical in phase 1 and phase 2b.
__device__ __forceinline__ float neg_dist(float4 q2, float4 c) {
    return fmaf(q2.x, c.x, fmaf(q2.y, c.y, fmaf(q2.z, c.z, -q2.w))) - c.w;
}

// ---------------------------------------------------------------------------
// prep_kernel = KNN (blocks 0..1023) + weight convert/swizzle (blocks 1024+).
// Also zeroes nm_acc + arrival counters every launch (replay-safe).
// ---------------------------------------------------------------------------
__global__ __launch_bounds__(256) void prep_kernel(
    const float* __restrict__ pts, float* __restrict__ m_out,
    const float* __restrict__ bd0, const float* __restrict__ bW0,
    const float* __restrict__ bd1, const float* __restrict__ bW1,
    const float* __restrict__ bWs, u16* __restrict__ Wswz,
    float* __restrict__ nm_acc)
{
    __shared__ float4 sp[N_PTS];                      // 32 KB (knn branch only)
    if (blockIdx.x >= 1024) {
        int i = (blockIdx.x - 1024) * 256 + threadIdx.x;
        if (i >= WTOT) return;
        if (i < 5*NM_BLK + 32) nm_acc[i] = 0.f;       // replica sums + counters
        float v; int base, K, local;
        if (i < 327680)      { int rel = i;          base = (rel/65536)*65536;            local = rel%65536; K = 256; v = bd0[rel]; }
        else if (i < 491520) { int rel = i - 327680; base = 327680 + (rel/32768)*32768;   local = rel%32768; K = 256; v = bW0[rel]; }
        else if (i < 573440) { int rel = i - 491520; base = 491520 + (rel/16384)*16384;   local = rel%16384; K = 128; v = bd1[rel]; }
        else if (i < 655360) { int rel = i - 573440; base = 573440 + (rel/16384)*16384;   local = rel%16384; K = 128; v = bW1[rel]; }
        else                 { int rel = i - 655360; base = 655360 + (rel/32768)*32768;   local = rel%32768; K = 256; v = bWs[rel]; }
        int m = local / K, k = local % K;
        int NKF = K >> 5;
        int mf = m >> 4, r = m & 15;
        int kf = k >> 5, q = (k >> 3) & 3, ii = k & 7;
        int lane = q*16 + r;
        int dst = base + ((mf*NKF + kf)*64 + lane)*8 + ii;
        f16 h, l; split2h(v, h, l);
        f16* W = (f16*)Wswz;
        W[dst] = h; W[WTOT + dst] = l;
        return;
    }

    // ---- KNN ----
    const int b     = blockIdx.x >> 8;
    const int qbase = (blockIdx.x & 255) << 3;
    const int ql    = threadIdx.x >> 5;
    const int sl    = threadIdx.x & 31;
    const float* pb = pts + (size_t)b * N_PTS * 3;
    for (int i = threadIdx.x; i < N_PTS; i += 256) {
        float x = pb[i*3+0], y = pb[i*3+1], z = pb[i*3+2];
        sp[i] = make_float4(x, y, z, x*x + y*y + z*z);
    }
    __syncthreads();

    const int n = qbase + ql;
    const float4 q = sp[n];
    const float4 q2 = make_float4(2.f*q.x, 2.f*q.y, 2.f*q.z, q.w);

    float t[K_D];
#pragma unroll
    for (int s = 0; s < K_D; ++s) t[s] = -INFINITY;

    for (int j = 0; j < N_PTS/32; ++j) {
        float4 c = sp[j*32 + sl];
        float v = neg_dist(q2, c);
#pragma unroll
        for (int s = 0; s < K_D; ++s) {
            float nx = (s < K_D-1) ? t[s+1] : INFINITY;
            t[s] = fminf(fmaxf(t[s], v), nx);
        }
    }

    float head = t[K_D-1];
    float T = -INFINITY;
#pragma unroll 1
    for (int e = 0; e < K_NN; ++e) {
        float v = head; int w = sl;
#pragma unroll
        for (int off = 1; off < 32; off <<= 1) {
            float vo = __shfl_xor(v, off);
            int   wo = __shfl_xor(w, off);
            bool take = (vo > v) || (vo == v && wo < w);
            v = take ? vo : v;
            w = take ? wo : w;
        }
        T = v;
        if (w == sl) {
#pragma unroll
            for (int s = K_D-1; s > 0; --s) t[s] = t[s-1];
            t[0] = -INFINITY;
            head = t[K_D-1];
        }
    }

    float sx = 0.f, sy = 0.f, sz = 0.f;
    for (int j = 0; j < N_PTS/32; ++j) {
        float4 c = sp[j*32 + sl];
        float v = neg_dist(q2, c);
        if (v >= T) { sx += c.x; sy += c.y; sz += c.z; }
    }
#pragma unroll
    for (int off = 1; off < 32; off <<= 1) {
        sx += __shfl_xor(sx, off);
        sy += __shfl_xor(sy, off);
        sz += __shfl_xor(sz, off);
    }
    if (sl == 0) {
        const float inv = 1.0f / (float)K_NN;
        const int pt = b * N_PTS + n;
        m_out[pt*3+0] = sx * inv;
        m_out[pt*3+1] = sy * inv;
        m_out[pt*3+2] = sz * inv;
    }
}

// ---------------------------------------------------------------------------
// MFMA GEMM cores — R6 measured-good form (runtime kf bounds, compact
// `#pragma unroll 1` loop, depth-1 Aa/Ab ping-pong; full unroll SPILLS to
// scratch: R7 showed +28 MB HBM writes), with NK and B-stride as COMPILE-TIME
// template constants so per-load address math strength-reduces (no v_mul).
// Consecutive kf ranges preserve accumulate order (bit-identical).
// ---------------------------------------------------------------------------
template<int MF, int JF, int NK, int BS>
__device__ __forceinline__ void run_gemm_hi(
    const f16* __restrict__ Whi, size_t aoff,
    int kf0, int kf1, const f16* Blds, int lane,
    floatx4 (&acc)[MF][JF])
{
    const int l15 = lane & 15;
    const int lq8 = (lane >> 4) * 8;
    half8 Aa[MF], Ab[MF];

    auto loada = [&](half8 (&dst)[MF], int kf) {
#pragma unroll
        for (int fm = 0; fm < MF; ++fm)
            dst[fm] = *(const half8*)(Whi + aoff + (size_t)fm*NK*512 + (size_t)kf*512 + (size_t)lane*8);
    };
    auto step = [&](half8 (&af)[MF], int kf) {
        half8 bq[JF];
#pragma unroll
        for (int fj = 0; fj < JF; ++fj)
            bq[fj] = *(const half8*)&Blds[(fj*16 + l15)*BS + kf*32 + lq8];
#pragma unroll
        for (int fm = 0; fm < MF; ++fm)
#pragma unroll
            for (int fj = 0; fj < JF; ++fj)
                acc[fm][fj] = __builtin_amdgcn_mfma_f32_16x16x32_f16(af[fm], bq[fj], acc[fm][fj], 0, 0, 0);
    };

    loada(Aa, kf0);
#pragma unroll 1
    for (int kf = kf0; kf < kf1; kf += 2) {
        loada(Ab, kf + 1);
        step(Aa, kf);
        if (kf + 2 < kf1) loada(Aa, kf + 2);
        step(Ab, kf + 1);
    }
}

template<int MF, int JF, int NK, int BS>
__device__ __forceinline__ void run_gemm_split(
    const f16* __restrict__ Whi, const f16* __restrict__ Wlo, size_t aoff,
    int kf0, int kf1, const f16* Blds, int lane,
    floatx4 (&acc)[MF][JF], floatx4 (&accL)[MF][JF])
{
    const int l15 = lane & 15;
    const int lq8 = (lane >> 4) * 8;
    half8 Aa[2*MF], Ab[2*MF];

    auto loada = [&](half8 (&dst)[2*MF], int kf) {
#pragma unroll
        for (int fm = 0; fm < MF; ++fm) {
            size_t fo = aoff + (size_t)fm*NK*512 + (size_t)kf*512 + (size_t)lane*8;
            dst[fm*2+0] = *(const half8*)(Whi + fo);
            dst[fm*2+1] = *(const half8*)(Wlo + fo);
        }
    };
    auto step = [&](half8 (&af)[2*MF], int kf) {
        half8 bq[JF];
#pragma unroll
        for (int fj = 0; fj < JF; ++fj)
            bq[fj] = *(const half8*)&Blds[(fj*16 + l15)*BS + kf*32 + lq8];
#pragma unroll
        for (int fm = 0; fm < MF; ++fm)
#pragma unroll
            for (int fj = 0; fj < JF; ++fj) {
                acc[fm][fj]  = __builtin_amdgcn_mfma_f32_16x16x32_f16(af[fm*2+0], bq[fj], acc[fm][fj], 0, 0, 0);
                accL[fm][fj] = __builtin_amdgcn_mfma_f32_16x16x32_f16(af[fm*2+1], bq[fj], accL[fm][fj], 0, 0, 0);
            }
    };

    loada(Aa, kf0);
#pragma unroll 1
    for (int kf = kf0; kf < kf1; kf += 2) {
        loada(Ab, kf + 1);
        step(Aa, kf);
        if (kf + 2 < kf1) loada(Aa, kf + 2);
        step(Ab, kf + 1);
    }
}

__device__ __forceinline__ uint2 pack_res(floatx4 a, floatx4 aL) {
    u16 hh[4];
#pragma unroll
    for (int r = 0; r < 4; ++r) {
        f16 hv = (f16)(a[r] + aL[r] * (1.0f/1024.0f));
        hh[r] = *(u16*)&hv;
    }
    uint2 pv;
    pv.x = (u32)hh[0] | ((u32)hh[1] << 16);
    pv.y = (u32)hh[2] | ((u32)hh[3] << 16);
    return pv;
}

__device__ __forceinline__ uint2 pack_hi(floatx4 a) {
    u16 hh[4];
#pragma unroll
    for (int r = 0; r < 4; ++r) {
        f16 hv = (f16)a[r];
        hh[r] = *(u16*)&hv;
    }
    uint2 pv;
    pv.x = (u32)hh[0] | ((u32)hh[1] << 16);
    pv.y = (u32)hh[2] | ((u32)hh[3] << 16);
    return pv;
}

// ---------------------------------------------------------------------------
// FUSED resnet, BIG-TILE + 2-D WAVE GRID + WAIT OVERLAP (R6 structure):
// 256 blocks x 512 thr (4(M) x 2(N) waves), 96 rows, 101 KB LDS, 1 block/CU.
// st>=1: gemm1/gemm4a own-K-half before the pool rendezvous, pooled half
// after. Sync cache-op-free (raw vmcnt(0) + relaxed atomics; __threadfence
// would emit buffer_wbl2/inv and evict the L2-resident weights).
// ---------------------------------------------------------------------------
__global__ __launch_bounds__(512, 2) void resnet_kernel(
    const u16* __restrict__ Wswz,
    const float* __restrict__ pts, const float* __restrict__ m_buf,
    const float* __restrict__ fcW,
    float* __restrict__ nm_acc, int* __restrict__ cnt,
    const float* __restrict__ act_d, const float* __restrict__ fc_c,
    float* __restrict__ out)
{
    extern __shared__ char smem_raw[];
    f16*   X  = (f16*)smem_raw;            // [ROWS*264] x (w256); later h/y2 @136
    f16*   Yd = X + ROWS*264;              // [ROWS*264] d/y (w256) | d1 @136
    float* YC = (float*)Yd;                // [ROWS*132] C floats | Hf | nmT

    const int tid   = threadIdx.x;                  // 0..511
    const int bB    = blockIdx.x / BPB;             // batch (64 blocks/batch)
    const int lane  = tid & 63;
    const int wv    = tid >> 6;                     // 0..7
    const int mwave = wv >> 1;                      // 0..3 (M-grid)
    const int ncol  = wv & 1;                       // 0..1 (N-grid)
    const f16* Whi = (const f16*)Wswz;
    const f16* Wlo = Whi + WTOT;

#pragma unroll 1
    for (int st = 0; st < 5; ++st) {
        const int offD0 = st*65536;
        const int offW0 = 327680 + st*32768;
        const int offD1 = 491520 + st*16384;
        const int offW1 = 573440 + st*16384;
        const int offWs = 655360 + st*32768;

        // ---- stage 0: build x from fcW/pts/m (later stages: own half set)
        if (st == 0) {
            float* Hf = YC;                 // W(768) p(96)@768 m(96)@864
            const int ptbase = blockIdx.x * 32;
            for (int i = tid; i < 768; i += 512) Hf[i] = fcW[i];
            if (tid < 192) Hf[768 + tid] = (tid < 96) ? pts[ptbase*3 + tid]
                                                      : m_buf[ptbase*3 + tid - 96];
            __syncthreads();
#pragma unroll 1
            for (int it = 0; it < 6; ++it) {
                int idx = tid + 512*it;             // 0..3071
                int r = idx >> 5;                   // j-row 0..95
                int cg = idx & 31;
                int l = r / 3, v = r - l*3;
                float pv0[3] = {Hf[768+l*3], Hf[768+l*3+1], Hf[768+l*3+2]};
                float mv0[3] = {Hf[864+l*3], Hf[864+l*3+1], Hf[864+l*3+2]};
                int v1 = (v==2) ? 0 : v+1;
                int v2 = (v==0) ? 2 : v-1;
                float av = mv0[v] - pv0[v];
                float bv = pv0[v];
                float cv = mv0[v1]*pv0[v2] - mv0[v2]*pv0[v1];
                half8 o;
#pragma unroll
                for (int k = 0; k < 8; ++k) {
                    int ch = cg*8 + k;
                    o[k] = (f16)(Hf[ch*3+0]*av + Hf[ch*3+1]*bv + Hf[ch*3+2]*cv);
                }
                *(half8*)&X[r*264 + cg*8] = o;
            }
            __syncthreads();
        }

        // accumulators: gemm1 (d) + carried net = Ws@x + W1@y2
        floatx4 acc1[4][3];
        floatx4 acc4[2][3], accL4[2][3];
#pragma unroll
        for (int a = 0; a < 4; ++a)
#pragma unroll
            for (int b = 0; b < 3; ++b) acc1[a][b] = (floatx4){0,0,0,0};
#pragma unroll
        for (int a = 0; a < 2; ++a)
#pragma unroll
            for (int b = 0; b < 3; ++b) { acc4[a][b] = (floatx4){0,0,0,0}; accL4[a][b] = (floatx4){0,0,0,0}; }

        if (st == 0) {
            // ---- gemm1 full K; store d -> Yd @264; then gemm4a full K ----
            run_gemm_hi<4,3,8,264>(Whi, (size_t)offD0 + (size_t)mwave*16384, 0, 8,
                                   X + ncol*48*264, lane, acc1);
#pragma unroll
            for (int fm = 0; fm < 4; ++fm)
#pragma unroll
                for (int fj = 0; fj < 3; ++fj) {
                    int mloc = mwave*64 + fm*16 + (lane>>4)*4;
                    int jl   = ncol*48 + fj*16 + (lane & 15);
                    *(uint2*)&Yd[jl*264 + mloc] = pack_hi(acc1[fm][fj]);
                }
            __syncthreads();
            run_gemm_split<2,3,8,264>(Whi, Wlo, (size_t)offWs + (size_t)mwave*8192, 0, 8,
                                      X + ncol*48*264, lane, acc4, accL4);
        } else {
            // ---- EARLY half (own channels, kf 0..3) before the rendezvous
            run_gemm_hi<4,3,8,264>(Whi, (size_t)offD0 + (size_t)mwave*16384, 0, 4,
                                   X + ncol*48*264, lane, acc1);
            run_gemm_split<2,3,8,264>(Whi, Wlo, (size_t)offWs + (size_t)mwave*8192, 0, 4,
                                      X + ncol*48*264, lane, acc4, accL4);

            // ---- rendezvous: wait for stage st-1 pool of this batch ------
            if (tid == 0) {
                while (__hip_atomic_load(&cnt[(st-1)*4+bB], __ATOMIC_RELAXED, __HIP_MEMORY_SCOPE_AGENT) < BPB)
                    __builtin_amdgcn_s_sleep(8);
            }
            __syncthreads();

            // ---- fill pooled half of X (cg 16..31) -----------------------
            float* nmSp = nm_acc + (size_t)(st-1)*NM_BLK;
            f16* nmT = Yd;                          // Yd dead until d-store
            if (tid < 384) {
                int v = tid >> 7, ch = tid & 127;
                float sum = 0.f;
#pragma unroll
                for (int rep = 0; rep < NM_REP; ++rep)
                    sum += __hip_atomic_load(nmSp + rep*NM_STRIDE + (bB*3+v)*128 + ch,
                                             __ATOMIC_RELAXED, __HIP_MEMORY_SCOPE_AGENT);
                nmT[tid] = (f16)(sum * (1.0f/2048.0f));
            }
            __syncthreads();
#pragma unroll 1
            for (int idx = tid; idx < 1536; idx += 512) {
                int r = idx >> 4;                   // 0..95
                int cg = (idx & 15) + 16;
                int v = r % 3;
                *(half8*)&X[r*264 + cg*8] = *(const half8*)&nmT[v*128 + (cg-16)*8];
            }
            __syncthreads();

            // ---- LATE half (pooled channels, kf 4..7); store d -----------
            run_gemm_hi<4,3,8,264>(Whi, (size_t)offD0 + (size_t)mwave*16384, 4, 8,
                                   X + ncol*48*264, lane, acc1);
#pragma unroll
            for (int fm = 0; fm < 4; ++fm)
#pragma unroll
                for (int fj = 0; fj < 3; ++fj) {
                    int mloc = mwave*64 + fm*16 + (lane>>4)*4;
                    int jl   = ncol*48 + fj*16 + (lane & 15);
                    *(uint2*)&Yd[jl*264 + mloc] = pack_hi(acc1[fm][fj]);
                }
            __syncthreads();
            run_gemm_split<2,3,8,264>(Whi, Wlo, (size_t)offWs + (size_t)mwave*8192, 4, 8,
                                      X + ncol*48*264, lane, acc4, accL4);
        }

        // ---- relu1: y = vnrelu(x, d), in place in Y (1024 items) ---------
#pragma unroll 1
        for (int it = 0; it < 2; ++it) {
            int idx = tid + 512*it;
            int l = idx >> 5, cg = idx & 31;      // l 0..31, cg 0..31
            half8 xa = *(const half8*)&X[(l*3+0)*264 + cg*8];
            half8 xb = *(const half8*)&X[(l*3+1)*264 + cg*8];
            half8 xc = *(const half8*)&X[(l*3+2)*264 + cg*8];
            half8 da = *(const half8*)&Yd[(l*3+0)*264 + cg*8];
            half8 db = *(const half8*)&Yd[(l*3+1)*264 + cg*8];
            half8 dc = *(const half8*)&Yd[(l*3+2)*264 + cg*8];
            half8 ya, yb, yc;
#pragma unroll
            for (int k = 0; k < 8; ++k) {
                float x0 = (float)xa[k], x1 = (float)xb[k], x2 = (float)xc[k];
                float d0 = (float)da[k], d1 = (float)db[k], d2 = (float)dc[k];
                float dot = x0*d0 + x1*d1 + x2*d2;
                float y0, y1, y2;
                if (dot >= 0.f) { y0 = x0; y1 = x1; y2 = x2; }
                else {
                    float dsq = d0*d0 + d1*d1 + d2*d2 + 1e-8f;
                    float sc = dot / dsq;
                    y0 = x0 - sc*d0; y1 = x1 - sc*d1; y2 = x2 - sc*d2;
                }
                ya[k] = (f16)y0; yb[k] = (f16)y1; yc[k] = (f16)y2;
            }
            *(half8*)&Yd[(l*3+0)*264 + cg*8] = ya;
            *(half8*)&Yd[(l*3+1)*264 + cg*8] = yb;
            *(half8*)&Yd[(l*3+2)*264 + cg*8] = yc;
        }
        __syncthreads();      // all waves past gemm4a (X free) and relu1

        // ---- gemm2: h = W0 @ y (split), h -> X region @136 ---------------
        {
            floatx4 acc[2][3], accL[2][3];
#pragma unroll
            for (int a = 0; a < 2; ++a)
#pragma unroll
                for (int b = 0; b < 3; ++b) { acc[a][b] = (floatx4){0,0,0,0}; accL[a][b] = (floatx4){0,0,0,0}; }
            run_gemm_split<2,3,8,264>(Whi, Wlo, (size_t)offW0 + (size_t)mwave*8192, 0, 8,
                                      Yd + ncol*48*264, lane, acc, accL);
#pragma unroll
            for (int fm = 0; fm < 2; ++fm)
#pragma unroll
                for (int fj = 0; fj < 3; ++fj) {
                    int mloc = mwave*32 + fm*16 + (lane>>4)*4;
                    int jl   = ncol*48 + fj*16 + (lane & 15);
                    *(uint2*)&X[jl*136 + mloc] = pack_res(acc[fm][fj], accL[fm][fj]);
                }
        }
        __syncthreads();

        // ---- gemm3: d1 = D1 @ h (hi-only), d1 -> Y @136 ------------------
        {
            floatx4 acc[2][3];
#pragma unroll
            for (int a = 0; a < 2; ++a)
#pragma unroll
                for (int b = 0; b < 3; ++b) acc[a][b] = (floatx4){0,0,0,0};
            run_gemm_hi<2,3,4,136>(Whi, (size_t)offD1 + (size_t)mwave*4096, 0, 4,
                                   X + ncol*48*136, lane, acc);
#pragma unroll
            for (int fm = 0; fm < 2; ++fm)
#pragma unroll
                for (int fj = 0; fj < 3; ++fj) {
                    int mloc = mwave*32 + fm*16 + (lane>>4)*4;
                    int jl   = ncol*48 + fj*16 + (lane & 15);
                    *(uint2*)&Yd[jl*136 + mloc] = pack_hi(acc[fm][fj]);
                }
        }
        __syncthreads();

        // ---- relu2: y2 = vnrelu(h, d1), over h in X @136 (512 items) -----
        {
            int l = tid >> 4, cg = tid & 15;      // l 0..31, cg 0..15
            half8 xa = *(const half8*)&X[(l*3+0)*136 + cg*8];
            half8 xb = *(const half8*)&X[(l*3+1)*136 + cg*8];
            half8 xc = *(const half8*)&X[(l*3+2)*136 + cg*8];
            half8 da = *(const half8*)&Yd[(l*3+0)*136 + cg*8];
            half8 db = *(const half8*)&Yd[(l*3+1)*136 + cg*8];
            half8 dc = *(const half8*)&Yd[(l*3+2)*136 + cg*8];
            half8 ya, yb, yc;
#pragma unroll
            for (int k = 0; k < 8; ++k) {
                float x0 = (float)xa[k], x1 = (float)xb[k], x2 = (float)xc[k];
                float d0 = (float)da[k], d1 = (float)db[k], d2 = (float)dc[k];
                float dot = x0*d0 + x1*d1 + x2*d2;
                float y0, y1, y2;
                if (dot >= 0.f) { y0 = x0; y1 = x1; y2 = x2; }
                else {
                    float dsq = d0*d0 + d1*d1 + d2*d2 + 1e-8f;
                    float sc = dot / dsq;
                    y0 = x0 - sc*d0; y1 = x1 - sc*d1; y2 = x2 - sc*d2;
                }
                ya[k] = (f16)y0; yb[k] = (f16)y1; yc[k] = (f16)y2;
            }
            *(half8*)&X[(l*3+0)*136 + cg*8] = ya;   // per-thread-private rows
            *(half8*)&X[(l*3+1)*136 + cg*8] = yb;
            *(half8*)&X[(l*3+2)*136 + cg*8] = yc;
        }
        __syncthreads();

        // ---- gemm4b: acc4 += W1 @ y2 (split), B = X @136 -----------------
        run_gemm_split<2,3,4,136>(Whi, Wlo, (size_t)offW1 + (size_t)mwave*4096, 0, 4,
                                  X + ncol*48*136, lane, acc4, accL4);
        __syncthreads();      // X (@136) dead; safe to rewrite X @264

        // ---- epilogue: next-stage x (f16) -> X @264 cg<16; C -> Y --------
#pragma unroll
        for (int fm = 0; fm < 2; ++fm)
#pragma unroll
            for (int fj = 0; fj < 3; ++fj) {
                int mloc = mwave*32 + fm*16 + (lane>>4)*4;
                int jl   = ncol*48 + fj*16 + (lane & 15);
                floatx4 res;
#pragma unroll
                for (int r = 0; r < 4; ++r) res[r] = acc4[fm][fj][r] + accL4[fm][fj][r] * (1.0f/1024.0f);
                *(uint2*)&X[jl*264 + mloc] = pack_res(acc4[fm][fj], accL4[fm][fj]);
                *(floatx4*)&YC[jl*132 + mloc] = res;
            }
        __syncthreads();

        // ---- pool: sum 32 points per (v, ch) -> replica atomics ----------
        const int rsel = (blockIdx.x & (NM_REP-1)) * NM_STRIDE;
        float* nmS = nm_acc + (size_t)st*NM_BLK;
        if (tid < 384) {
            int v = tid >> 7, ch = tid & 127;
            float sum = 0.f;
#pragma unroll 1
            for (int pt = 0; pt < 32; ++pt) sum += YC[(pt*3+v)*132 + ch];
            atomicAdd(nmS + rsel + (bB*3+v)*128 + ch, sum);
        }
        // Producer ordering WITHOUT cache ops: drain this thread's atomics,
        // then barrier (covers the whole block).
        asm volatile("s_waitcnt vmcnt(0)" ::: "memory");
        __syncthreads();
        if (tid == 0)
            __hip_atomic_fetch_add(&cnt[st*4+bB], 1, __ATOMIC_RELAXED, __HIP_MEMORY_SCOPE_AGENT);
        // NOTE: the wait + pooled-fill for the next stage happens INSIDE
        // the next iteration, after its early-half gemms.
    }

    // ---- folded head: blocks 0..3 compute out[b] -------------------------
    if (blockIdx.x < 4) {
        const int b = blockIdx.x;
        if (tid == 0) {
            while (__hip_atomic_load(&cnt[16+b], __ATOMIC_RELAXED, __HIP_MEMORY_SCOPE_AGENT) < BPB)
                __builtin_amdgcn_s_sleep(8);
        }
        __syncthreads();
        float* xs = (float*)smem_raw;               // [128][3]
        float* ys = xs + 384;
        const float* nm4 = nm_acc + (size_t)4*NM_BLK;
        if (tid < 128) {
            int c = tid;
            float s0 = 0.f, s1 = 0.f, s2 = 0.f;
#pragma unroll
            for (int rep = 0; rep < NM_REP; ++rep) {
                s0 += __hip_atomic_load(nm4 + rep*NM_STRIDE + (b*3+0)*128 + c, __ATOMIC_RELAXED, __HIP_MEMORY_SCOPE_AGENT);
                s1 += __hip_atomic_load(nm4 + rep*NM_STRIDE + (b*3+1)*128 + c, __ATOMIC_RELAXED, __HIP_MEMORY_SCOPE_AGENT);
                s2 += __hip_atomic_load(nm4 + rep*NM_STRIDE + (b*3+2)*128 + c, __ATOMIC_RELAXED, __HIP_MEMORY_SCOPE_AGENT);
            }
            xs[c*3+0] = s0 * (1.0f/2048.0f);
            xs[c*3+1] = s1 * (1.0f/2048.0f);
            xs[c*3+2] = s2 * (1.0f/2048.0f);
        }
        __syncthreads();
        if (tid < 128) {
            int c = tid;
            float d0 = 0.f, d1 = 0.f, d2 = 0.f;
            for (int i = 0; i < 128; ++i) {
                float w = act_d[c*128 + i];
                d0 = fmaf(w, xs[i*3+0], d0);
                d1 = fmaf(w, xs[i*3+1], d1);
                d2 = fmaf(w, xs[i*3+2], d2);
            }
            float x0 = xs[c*3+0], x1 = xs[c*3+1], x2 = xs[c*3+2];
            float dot = x0*d0 + x1*d1 + x2*d2;
            float y0, y1, y2;
            if (dot >= 0.f) { y0 = x0; y1 = x1; y2 = x2; }
            else {
                float dsq = d0*d0 + d1*d1 + d2*d2 + 1e-8f;
                float sc = dot / dsq;
                y0 = x0 - sc*d0; y1 = x1 - sc*d1; y2 = x2 - sc*d2;
            }
            ys[c*3+0] = y0; ys[c*3+1] = y1; ys[c*3+2] = y2;
        }
        __syncthreads();
        if (tid < 128) {
            int c = tid;
            float o0 = 0.f, o1 = 0.f, o2 = 0.f;
            for (int i = 0; i < 128; ++i) {
                float w = fc_c[c*128 + i];
                o0 = fmaf(w, ys[i*3+0], o0);
                o1 = fmaf(w, ys[i*3+1], o1);
                o2 = fmaf(w, ys[i*3+2], o2);
            }
            out[b*384 + c*3 + 0] = o0;
            out[b*384 + c*3 + 1] = o1;
            out[b*384 + c*3 + 2] = o2;
        }
    }
}

// ---------------------------------------------------------------------------
extern "C" void kernel_launch(void* const* d_in, const int* in_sizes, int n_in,
                              void* d_out, int out_size, void* d_ws, size_t ws_size,
                              hipStream_t stream)
{
    const float* p      = (const float*)d_in[0];
    const float* fc_pos = (const float*)d_in[1];
    const float* bd0    = (const float*)d_in[2];
    const float* bW0    = (const float*)d_in[3];
    const float* bd1    = (const float*)d_in[4];
    const float* bW1    = (const float*)d_in[5];
    const float* bWs    = (const float*)d_in[6];
    const float* fc_c   = (const float*)d_in[7];
    const float* act_d  = (const float*)d_in[8];
    float* out = (float*)d_out;

    // Workspace layout (16B-aligned)
    char* w = (char*)d_ws;
    float* m_buf  = (float*)w;  w += 98304;                  // knn means
    float* nm_acc = (float*)w;  w += (size_t)5*NM_BLK*4;     // replicated pool sums
    int*   cnt    = (int*)w;    w += 128;                    // arrival counters (zeroed w/ nm)
    u16*   Wswz   = (u16*)w;    w += (size_t)2*WTOT*2;       // swizzled split weights

    static bool attr_set = false;
    if (!attr_set) {
        hipFuncSetAttribute((const void*)resnet_kernel,
                            hipFuncAttributeMaxDynamicSharedMemorySize, LDS_BYTES);
        attr_set = true;
    }

    prep_kernel<<<dim3(1024 + 3200), dim3(256), 0, stream>>>(
        p, m_buf, bd0, bW0, bd1, bW1, bWs, Wswz, nm_acc);

    resnet_kernel<<<dim3(NBLK), dim3(512), LDS_BYTES, stream>>>(
        Wswz, p, m_buf, fc_pos, nm_acc, cnt, act_d, fc_c, out);

    (void)in_sizes; (void)n_in; (void)out_size; (void)ws_size;
}

// Round 10
// 213.846 us; speedup vs baseline: 1.2484x; 1.0090x over previous
//
#include <hip/hip_runtime.h>
#include <math.h>

#define N_PTS 2048
#define K_NN  20
#define K_D   10              // per-slice kept depth
#define WTOT  819200          // total weight elements across the 5 tensors
#define NM_REP 8              // pool-accumulator replicas
#define NM_STRIDE 1536        // floats per replica slot (4 batches * 3 * 128)
#define NM_BLK (NM_REP*NM_STRIDE)
#define NBLK 256              // resnet blocks (32 points each)
#define BPB  64               // blocks per batch
#define ROWS 96               // j-rows per block (32 points * 3)
#define LDS_BYTES (2*ROWS*264*2)   // X + Y regions, 101376 B

typedef unsigned short u16;
typedef unsigned int   u32;
typedef _Float16 f16;
using half8   = __attribute__((ext_vector_type(8))) _Float16;
using floatx4 = __attribute__((ext_vector_type(4))) float;

// Weights: split fp16.  w ~= hi + lo/1024, |err| ~ 2^-24 |w|.
__device__ __forceinline__ void split2h(float v, f16& h, f16& l) {
    h = (f16)v;
    l = (f16)((v - (float)h) * 1024.0f);
}

// nd must be bit-identical in phase 1 and phase 2b.
__device__ __forceinline__ float neg_dist(float4 q2, float4 c) {
    return fmaf(q2.x, c.x, fmaf(q2.y, c.y, fmaf(q2.z, c.z, -q2.w))) - c.w;
}

// ---------------------------------------------------------------------------
// prep_kernel = KNN (blocks 0..1023) + weight convert/swizzle (blocks 1024+).
// Also zeroes nm_acc + arrival counters every launch (replay-safe).
// ---------------------------------------------------------------------------
__global__ __launch_bounds__(256) void prep_kernel(
    const float* __restrict__ pts, float* __restrict__ m_out,
    const float* __restrict__ bd0, const float* __restrict__ bW0,
    const float* __restrict__ bd1, const float* __restrict__ bW1,
    const float* __restrict__ bWs, u16* __restrict__ Wswz,
    float* __restrict__ nm_acc)
{
    __shared__ float4 sp[N_PTS];                      // 32 KB (knn branch only)
    if (blockIdx.x >= 1024) {
        int i = (blockIdx.x - 1024) * 256 + threadIdx.x;
        if (i >= WTOT) return;
        if (i < 5*NM_BLK + 32) nm_acc[i] = 0.f;       // replica sums + counters
        float v; int base, K, local;
        if (i < 327680)      { int rel = i;          base = (rel/65536)*65536;            local = rel%65536; K = 256; v = bd0[rel]; }
        else if (i < 491520) { int rel = i - 327680; base = 327680 + (rel/32768)*32768;   local = rel%32768; K = 256; v = bW0[rel]; }
        else if (i < 573440) { int rel = i - 491520; base = 491520 + (rel/16384)*16384;   local = rel%16384; K = 128; v = bd1[rel]; }
        else if (i < 655360) { int rel = i - 573440; base = 573440 + (rel/16384)*16384;   local = rel%16384; K = 128; v = bW1[rel]; }
        else                 { int rel = i - 655360; base = 655360 + (rel/32768)*32768;   local = rel%32768; K = 256; v = bWs[rel]; }
        int m = local / K, k = local % K;
        int NKF = K >> 5;
        int mf = m >> 4, r = m & 15;
        int kf = k >> 5, q = (k >> 3) & 3, ii = k & 7;
        int lane = q*16 + r;
        int dst = base + ((mf*NKF + kf)*64 + lane)*8 + ii;
        f16 h, l; split2h(v, h, l);
        f16* W = (f16*)Wswz;
        W[dst] = h; W[WTOT + dst] = l;
        return;
    }

    // ---- KNN ----
    const int b     = blockIdx.x >> 8;
    const int qbase = (blockIdx.x & 255) << 3;
    const int ql    = threadIdx.x >> 5;
    const int sl    = threadIdx.x & 31;
    const float* pb = pts + (size_t)b * N_PTS * 3;
    for (int i = threadIdx.x; i < N_PTS; i += 256) {
        float x = pb[i*3+0], y = pb[i*3+1], z = pb[i*3+2];
        sp[i] = make_float4(x, y, z, x*x + y*y + z*z);
    }
    __syncthreads();

    const int n = qbase + ql;
    const float4 q = sp[n];
    const float4 q2 = make_float4(2.f*q.x, 2.f*q.y, 2.f*q.z, q.w);

    float t[K_D];
#pragma unroll
    for (int s = 0; s < K_D; ++s) t[s] = -INFINITY;

    for (int j = 0; j < N_PTS/32; ++j) {
        float4 c = sp[j*32 + sl];
        float v = neg_dist(q2, c);
#pragma unroll
        for (int s = 0; s < K_D; ++s) {
            float nx = (s < K_D-1) ? t[s+1] : INFINITY;
            t[s] = fminf(fmaxf(t[s], v), nx);
        }
    }

    float head = t[K_D-1];
    float T = -INFINITY;
#pragma unroll 1
    for (int e = 0; e < K_NN; ++e) {
        float v = head; int w = sl;
#pragma unroll
        for (int off = 1; off < 32; off <<= 1) {
            float vo = __shfl_xor(v, off);
            int   wo = __shfl_xor(w, off);
            bool take = (vo > v) || (vo == v && wo < w);
            v = take ? vo : v;
            w = take ? wo : w;
        }
        T = v;
        if (w == sl) {
#pragma unroll
            for (int s = K_D-1; s > 0; --s) t[s] = t[s-1];
            t[0] = -INFINITY;
            head = t[K_D-1];
        }
    }

    float sx = 0.f, sy = 0.f, sz = 0.f;
    for (int j = 0; j < N_PTS/32; ++j) {
        float4 c = sp[j*32 + sl];
        float v = neg_dist(q2, c);
        if (v >= T) { sx += c.x; sy += c.y; sz += c.z; }
    }
#pragma unroll
    for (int off = 1; off < 32; off <<= 1) {
        sx += __shfl_xor(sx, off);
        sy += __shfl_xor(sy, off);
        sz += __shfl_xor(sz, off);
    }
    if (sl == 0) {
        const float inv = 1.0f / (float)K_NN;
        const int pt = b * N_PTS + n;
        m_out[pt*3+0] = sx * inv;
        m_out[pt*3+1] = sy * inv;
        m_out[pt*3+2] = sz * inv;
    }
}

// ---------------------------------------------------------------------------
// MFMA GEMM cores — R8 measured-good form (runtime kf bounds, compact
// `#pragma unroll 1` loop, depth-1 Aa/Ab ping-pong; full unroll SPILLS to
// scratch: R7 showed +28 MB HBM writes), NK/B-stride compile-time.
// Consecutive kf ranges preserve accumulate order (bit-identical).
// ---------------------------------------------------------------------------
template<int MF, int JF, int NK, int BS>
__device__ __forceinline__ void run_gemm_hi(
    const f16* __restrict__ Whi, size_t aoff,
    int kf0, int kf1, const f16* Blds, int lane,
    floatx4 (&acc)[MF][JF])
{
    const int l15 = lane & 15;
    const int lq8 = (lane >> 4) * 8;
    half8 Aa[MF], Ab[MF];

    auto loada = [&](half8 (&dst)[MF], int kf) {
#pragma unroll
        for (int fm = 0; fm < MF; ++fm)
            dst[fm] = *(const half8*)(Whi + aoff + (size_t)fm*NK*512 + (size_t)kf*512 + (size_t)lane*8);
    };
    auto step = [&](half8 (&af)[MF], int kf) {
        half8 bq[JF];
#pragma unroll
        for (int fj = 0; fj < JF; ++fj)
            bq[fj] = *(const half8*)&Blds[(fj*16 + l15)*BS + kf*32 + lq8];
#pragma unroll
        for (int fm = 0; fm < MF; ++fm)
#pragma unroll
            for (int fj = 0; fj < JF; ++fj)
                acc[fm][fj] = __builtin_amdgcn_mfma_f32_16x16x32_f16(af[fm], bq[fj], acc[fm][fj], 0, 0, 0);
    };

    loada(Aa, kf0);
#pragma unroll 1
    for (int kf = kf0; kf < kf1; kf += 2) {
        loada(Ab, kf + 1);
        step(Aa, kf);
        if (kf + 2 < kf1) loada(Aa, kf + 2);
        step(Ab, kf + 1);
    }
}

template<int MF, int JF, int NK, int BS>
__device__ __forceinline__ void run_gemm_split(
    const f16* __restrict__ Whi, const f16* __restrict__ Wlo, size_t aoff,
    int kf0, int kf1, const f16* Blds, int lane,
    floatx4 (&acc)[MF][JF], floatx4 (&accL)[MF][JF])
{
    const int l15 = lane & 15;
    const int lq8 = (lane >> 4) * 8;
    half8 Aa[2*MF], Ab[2*MF];

    auto loada = [&](half8 (&dst)[2*MF], int kf) {
#pragma unroll
        for (int fm = 0; fm < MF; ++fm) {
            size_t fo = aoff + (size_t)fm*NK*512 + (size_t)kf*512 + (size_t)lane*8;
            dst[fm*2+0] = *(const half8*)(Whi + fo);
            dst[fm*2+1] = *(const half8*)(Wlo + fo);
        }
    };
    auto step = [&](half8 (&af)[2*MF], int kf) {
        half8 bq[JF];
#pragma unroll
        for (int fj = 0; fj < JF; ++fj)
            bq[fj] = *(const half8*)&Blds[(fj*16 + l15)*BS + kf*32 + lq8];
#pragma unroll
        for (int fm = 0; fm < MF; ++fm)
#pragma unroll
            for (int fj = 0; fj < JF; ++fj) {
                acc[fm][fj]  = __builtin_amdgcn_mfma_f32_16x16x32_f16(af[fm*2+0], bq[fj], acc[fm][fj], 0, 0, 0);
                accL[fm][fj] = __builtin_amdgcn_mfma_f32_16x16x32_f16(af[fm*2+1], bq[fj], accL[fm][fj], 0, 0, 0);
            }
    };

    loada(Aa, kf0);
#pragma unroll 1
    for (int kf = kf0; kf < kf1; kf += 2) {
        loada(Ab, kf + 1);
        step(Aa, kf);
        if (kf + 2 < kf1) loada(Aa, kf + 2);
        step(Ab, kf + 1);
    }
}

// ---------------------------------------------------------------------------
// MERGED gemm1+gemm4a: both consume the SAME B panel (x in LDS), so one
// kf-loop shares the 3 B ds_reads across 24 MFMAs (was 2x12 with separate
// B-reads) and keeps 8 A-loads in flight per step (2x the MLP). Accumulate
// order per acc chain is unchanged -> bit-identical. Depth-1 ping-pong
// retained (R7: deeper unroll spills).
// ---------------------------------------------------------------------------
template<int BS>
__device__ __forceinline__ void run_gemm_merged(
    const f16* __restrict__ Whi, const f16* __restrict__ Wlo,
    size_t aoff1, size_t aoff4,
    int kf0, int kf1, const f16* Blds, int lane,
    floatx4 (&acc1)[4][3], floatx4 (&acc4)[2][3], floatx4 (&accL4)[2][3])
{
    const int l15 = lane & 15;
    const int lq8 = (lane >> 4) * 8;
    half8 Aa1[4], Ab1[4], Aa4[4], Ab4[4];

    auto loada = [&](half8 (&d1)[4], half8 (&d4)[4], int kf) {
#pragma unroll
        for (int fm = 0; fm < 4; ++fm)
            d1[fm] = *(const half8*)(Whi + aoff1 + (size_t)fm*8*512 + (size_t)kf*512 + (size_t)lane*8);
#pragma unroll
        for (int fm = 0; fm < 2; ++fm) {
            size_t fo = aoff4 + (size_t)fm*8*512 + (size_t)kf*512 + (size_t)lane*8;
            d4[fm*2+0] = *(const half8*)(Whi + fo);
            d4[fm*2+1] = *(const half8*)(Wlo + fo);
        }
    };
    auto step = [&](half8 (&a1)[4], half8 (&a4)[4], int kf) {
        half8 bq[3];
#pragma unroll
        for (int fj = 0; fj < 3; ++fj)
            bq[fj] = *(const half8*)&Blds[(fj*16 + l15)*BS + kf*32 + lq8];
#pragma unroll
        for (int fm = 0; fm < 4; ++fm)
#pragma unroll
            for (int fj = 0; fj < 3; ++fj)
                acc1[fm][fj] = __builtin_amdgcn_mfma_f32_16x16x32_f16(a1[fm], bq[fj], acc1[fm][fj], 0, 0, 0);
#pragma unroll
        for (int fm = 0; fm < 2; ++fm)
#pragma unroll
            for (int fj = 0; fj < 3; ++fj) {
                acc4[fm][fj]  = __builtin_amdgcn_mfma_f32_16x16x32_f16(a4[fm*2+0], bq[fj], acc4[fm][fj], 0, 0, 0);
                accL4[fm][fj] = __builtin_amdgcn_mfma_f32_16x16x32_f16(a4[fm*2+1], bq[fj], accL4[fm][fj], 0, 0, 0);
            }
    };

    loada(Aa1, Aa4, kf0);
#pragma unroll 1
    for (int kf = kf0; kf < kf1; kf += 2) {
        loada(Ab1, Ab4, kf + 1);
        step(Aa1, Aa4, kf);
        if (kf + 2 < kf1) loada(Aa1, Aa4, kf + 2);
        step(Ab1, Ab4, kf + 1);
    }
}

__device__ __forceinline__ uint2 pack_res(floatx4 a, floatx4 aL) {
    u16 hh[4];
#pragma unroll
    for (int r = 0; r < 4; ++r) {
        f16 hv = (f16)(a[r] + aL[r] * (1.0f/1024.0f));
        hh[r] = *(u16*)&hv;
    }
    uint2 pv;
    pv.x = (u32)hh[0] | ((u32)hh[1] << 16);
    pv.y = (u32)hh[2] | ((u32)hh[3] << 16);
    return pv;
}

__device__ __forceinline__ uint2 pack_hi(floatx4 a) {
    u16 hh[4];
#pragma unroll
    for (int r = 0; r < 4; ++r) {
        f16 hv = (f16)a[r];
        hh[r] = *(u16*)&hv;
    }
    uint2 pv;
    pv.x = (u32)hh[0] | ((u32)hh[1] << 16);
    pv.y = (u32)hh[2] | ((u32)hh[3] << 16);
    return pv;
}

// ---------------------------------------------------------------------------
// FUSED resnet, BIG-TILE + 2-D WAVE GRID + WAIT OVERLAP + MERGED gemm1/4a:
// 256 blocks x 512 thr (4(M) x 2(N) waves), 96 rows, 101 KB LDS, 1 block/CU.
// st>=1: merged own-K-half before the pool rendezvous, pooled half after.
// Sync cache-op-free (raw vmcnt(0) + relaxed atomics; __threadfence would
// emit buffer_wbl2/inv and evict the L2-resident weights).
// ---------------------------------------------------------------------------
__global__ __launch_bounds__(512, 2) void resnet_kernel(
    const u16* __restrict__ Wswz,
    const float* __restrict__ pts, const float* __restrict__ m_buf,
    const float* __restrict__ fcW,
    float* __restrict__ nm_acc, int* __restrict__ cnt,
    const float* __restrict__ act_d, const float* __restrict__ fc_c,
    float* __restrict__ out)
{
    extern __shared__ char smem_raw[];
    f16*   X  = (f16*)smem_raw;            // [ROWS*264] x (w256); later h/y2 @136
    f16*   Yd = X + ROWS*264;              // [ROWS*264] d/y (w256) | d1 @136
    float* YC = (float*)Yd;                // [ROWS*132] C floats | Hf | nmT

    const int tid   = threadIdx.x;                  // 0..511
    const int bB    = blockIdx.x / BPB;             // batch (64 blocks/batch)
    const int lane  = tid & 63;
    const int wv    = tid >> 6;                     // 0..7
    const int mwave = wv >> 1;                      // 0..3 (M-grid)
    const int ncol  = wv & 1;                       // 0..1 (N-grid)
    const f16* Whi = (const f16*)Wswz;
    const f16* Wlo = Whi + WTOT;

#pragma unroll 1
    for (int st = 0; st < 5; ++st) {
        const int offD0 = st*65536;
        const int offW0 = 327680 + st*32768;
        const int offD1 = 491520 + st*16384;
        const int offW1 = 573440 + st*16384;
        const int offWs = 655360 + st*32768;

        // ---- stage 0: build x from fcW/pts/m (later stages: own half set)
        if (st == 0) {
            float* Hf = YC;                 // W(768) p(96)@768 m(96)@864
            const int ptbase = blockIdx.x * 32;
            for (int i = tid; i < 768; i += 512) Hf[i] = fcW[i];
            if (tid < 192) Hf[768 + tid] = (tid < 96) ? pts[ptbase*3 + tid]
                                                      : m_buf[ptbase*3 + tid - 96];
            __syncthreads();
#pragma unroll 1
            for (int it = 0; it < 6; ++it) {
                int idx = tid + 512*it;             // 0..3071
                int r = idx >> 5;                   // j-row 0..95
                int cg = idx & 31;
                int l = r / 3, v = r - l*3;
                float pv0[3] = {Hf[768+l*3], Hf[768+l*3+1], Hf[768+l*3+2]};
                float mv0[3] = {Hf[864+l*3], Hf[864+l*3+1], Hf[864+l*3+2]};
                int v1 = (v==2) ? 0 : v+1;
                int v2 = (v==0) ? 2 : v-1;
                float av = mv0[v] - pv0[v];
                float bv = pv0[v];
                float cv = mv0[v1]*pv0[v2] - mv0[v2]*pv0[v1];
                half8 o;
#pragma unroll
                for (int k = 0; k < 8; ++k) {
                    int ch = cg*8 + k;
                    o[k] = (f16)(Hf[ch*3+0]*av + Hf[ch*3+1]*bv + Hf[ch*3+2]*cv);
                }
                *(half8*)&X[r*264 + cg*8] = o;
            }
            __syncthreads();
        }

        // accumulators: gemm1 (d) + carried net = Ws@x + W1@y2
        floatx4 acc1[4][3];
        floatx4 acc4[2][3], accL4[2][3];
#pragma unroll
        for (int a = 0; a < 4; ++a)
#pragma unroll
            for (int b = 0; b < 3; ++b) acc1[a][b] = (floatx4){0,0,0,0};
#pragma unroll
        for (int a = 0; a < 2; ++a)
#pragma unroll
            for (int b = 0; b < 3; ++b) { acc4[a][b] = (floatx4){0,0,0,0}; accL4[a][b] = (floatx4){0,0,0,0}; }

        const size_t aoff1 = (size_t)offD0 + (size_t)mwave*16384;
        const size_t aoff4 = (size_t)offWs + (size_t)mwave*8192;

        if (st == 0) {
            // ---- merged gemm1+gemm4a, full K; then store d -> Yd @264 ----
            run_gemm_merged<264>(Whi, Wlo, aoff1, aoff4, 0, 8,
                                 X + ncol*48*264, lane, acc1, acc4, accL4);
        } else {
            // ---- EARLY half (own channels, kf 0..3) before the rendezvous
            run_gemm_merged<264>(Whi, Wlo, aoff1, aoff4, 0, 4,
                                 X + ncol*48*264, lane, acc1, acc4, accL4);

            // ---- rendezvous: wait for stage st-1 pool of this batch ------
            if (tid == 0) {
                while (__hip_atomic_load(&cnt[(st-1)*4+bB], __ATOMIC_RELAXED, __HIP_MEMORY_SCOPE_AGENT) < BPB)
                    __builtin_amdgcn_s_sleep(8);
            }
            __syncthreads();

            // ---- fill pooled half of X (cg 16..31) -----------------------
            float* nmSp = nm_acc + (size_t)(st-1)*NM_BLK;
            f16* nmT = Yd;                          // Yd dead until d-store
            if (tid < 384) {
                int v = tid >> 7, ch = tid & 127;
                float sum = 0.f;
#pragma unroll
                for (int rep = 0; rep < NM_REP; ++rep)
                    sum += __hip_atomic_load(nmSp + rep*NM_STRIDE + (bB*3+v)*128 + ch,
                                             __ATOMIC_RELAXED, __HIP_MEMORY_SCOPE_AGENT);
                nmT[tid] = (f16)(sum * (1.0f/2048.0f));
            }
            __syncthreads();
#pragma unroll 1
            for (int idx = tid; idx < 1536; idx += 512) {
                int r = idx >> 4;                   // 0..95
                int cg = (idx & 15) + 16;
                int v = r % 3;
                *(half8*)&X[r*264 + cg*8] = *(const half8*)&nmT[v*128 + (cg-16)*8];
            }
            __syncthreads();

            // ---- LATE half (pooled channels, kf 4..7) --------------------
            run_gemm_merged<264>(Whi, Wlo, aoff1, aoff4, 4, 8,
                                 X + ncol*48*264, lane, acc1, acc4, accL4);
        }

        // ---- store d -> Yd @264 ------------------------------------------
#pragma unroll
        for (int fm = 0; fm < 4; ++fm)
#pragma unroll
            for (int fj = 0; fj < 3; ++fj) {
                int mloc = mwave*64 + fm*16 + (lane>>4)*4;
                int jl   = ncol*48 + fj*16 + (lane & 15);
                *(uint2*)&Yd[jl*264 + mloc] = pack_hi(acc1[fm][fj]);
            }
        __syncthreads();

        // ---- relu1: y = vnrelu(x, d), in place in Y (1024 items) ---------
#pragma unroll 1
        for (int it = 0; it < 2; ++it) {
            int idx = tid + 512*it;
            int l = idx >> 5, cg = idx & 31;      // l 0..31, cg 0..31
            half8 xa = *(const half8*)&X[(l*3+0)*264 + cg*8];
            half8 xb = *(const half8*)&X[(l*3+1)*264 + cg*8];
            half8 xc = *(const half8*)&X[(l*3+2)*264 + cg*8];
            half8 da = *(const half8*)&Yd[(l*3+0)*264 + cg*8];
            half8 db = *(const half8*)&Yd[(l*3+1)*264 + cg*8];
            half8 dc = *(const half8*)&Yd[(l*3+2)*264 + cg*8];
            half8 ya, yb, yc;
#pragma unroll
            for (int k = 0; k < 8; ++k) {
                float x0 = (float)xa[k], x1 = (float)xb[k], x2 = (float)xc[k];
                float d0 = (float)da[k], d1 = (float)db[k], d2 = (float)dc[k];
                float dot = x0*d0 + x1*d1 + x2*d2;
                float y0, y1, y2;
                if (dot >= 0.f) { y0 = x0; y1 = x1; y2 = x2; }
                else {
                    float dsq = d0*d0 + d1*d1 + d2*d2 + 1e-8f;
                    float sc = dot / dsq;
                    y0 = x0 - sc*d0; y1 = x1 - sc*d1; y2 = x2 - sc*d2;
                }
                ya[k] = (f16)y0; yb[k] = (f16)y1; yc[k] = (f16)y2;
            }
            *(half8*)&Yd[(l*3+0)*264 + cg*8] = ya;
            *(half8*)&Yd[(l*3+1)*264 + cg*8] = yb;
            *(half8*)&Yd[(l*3+2)*264 + cg*8] = yc;
        }
        __syncthreads();      // X free (merged gemm done) and y ready

        // ---- gemm2: h = W0 @ y (split), h -> X region @136 ---------------
        {
            floatx4 acc[2][3], accL[2][3];
#pragma unroll
            for (int a = 0; a < 2; ++a)
#pragma unroll
                for (int b = 0; b < 3; ++b) { acc[a][b] = (floatx4){0,0,0,0}; accL[a][b] = (floatx4){0,0,0,0}; }
            run_gemm_split<2,3,8,264>(Whi, Wlo, (size_t)offW0 + (size_t)mwave*8192, 0, 8,
                                      Yd + ncol*48*264, lane, acc, accL);
#pragma unroll
            for (int fm = 0; fm < 2; ++fm)
#pragma unroll
                for (int fj = 0; fj < 3; ++fj) {
                    int mloc = mwave*32 + fm*16 + (lane>>4)*4;
                    int jl   = ncol*48 + fj*16 + (lane & 15);
                    *(uint2*)&X[jl*136 + mloc] = pack_res(acc[fm][fj], accL[fm][fj]);
                }
        }
        __syncthreads();

        // ---- gemm3: d1 = D1 @ h (hi-only), d1 -> Y @136 ------------------
        {
            floatx4 acc[2][3];
#pragma unroll
            for (int a = 0; a < 2; ++a)
#pragma unroll
                for (int b = 0; b < 3; ++b) acc[a][b] = (floatx4){0,0,0,0};
            run_gemm_hi<2,3,4,136>(Whi, (size_t)offD1 + (size_t)mwave*4096, 0, 4,
                                   X + ncol*48*136, lane, acc);
#pragma unroll
            for (int fm = 0; fm < 2; ++fm)
#pragma unroll
                for (int fj = 0; fj < 3; ++fj) {
                    int mloc = mwave*32 + fm*16 + (lane>>4)*4;
                    int jl   = ncol*48 + fj*16 + (lane & 15);
                    *(uint2*)&Yd[jl*136 + mloc] = pack_hi(acc[fm][fj]);
                }
        }
        __syncthreads();

        // ---- relu2: y2 = vnrelu(h, d1), over h in X @136 (512 items) -----
        {
            int l = tid >> 4, cg = tid & 15;      // l 0..31, cg 0..15
            half8 xa = *(const half8*)&X[(l*3+0)*136 + cg*8];
            half8 xb = *(const half8*)&X[(l*3+1)*136 + cg*8];
            half8 xc = *(const half8*)&X[(l*3+2)*136 + cg*8];
            half8 da = *(const half8*)&Yd[(l*3+0)*136 + cg*8];
            half8 db = *(const half8*)&Yd[(l*3+1)*136 + cg*8];
            half8 dc = *(const half8*)&Yd[(l*3+2)*136 + cg*8];
            half8 ya, yb, yc;
#pragma unroll
            for (int k = 0; k < 8; ++k) {
                float x0 = (float)xa[k], x1 = (float)xb[k], x2 = (float)xc[k];
                float d0 = (float)da[k], d1 = (float)db[k], d2 = (float)dc[k];
                float dot = x0*d0 + x1*d1 + x2*d2;
                float y0, y1, y2;
                if (dot >= 0.f) { y0 = x0; y1 = x1; y2 = x2; }
                else {
                    float dsq = d0*d0 + d1*d1 + d2*d2 + 1e-8f;
                    float sc = dot / dsq;
                    y0 = x0 - sc*d0; y1 = x1 - sc*d1; y2 = x2 - sc*d2;
                }
                ya[k] = (f16)y0; yb[k] = (f16)y1; yc[k] = (f16)y2;
            }
            *(half8*)&X[(l*3+0)*136 + cg*8] = ya;   // per-thread-private rows
            *(half8*)&X[(l*3+1)*136 + cg*8] = yb;
            *(half8*)&X[(l*3+2)*136 + cg*8] = yc;
        }
        __syncthreads();

        // ---- gemm4b: acc4 += W1 @ y2 (split), B = X @136 -----------------
        run_gemm_split<2,3,4,136>(Whi, Wlo, (size_t)offW1 + (size_t)mwave*4096, 0, 4,
                                  X + ncol*48*136, lane, acc4, accL4);
        __syncthreads();      // X (@136) dead; safe to rewrite X @264

        // ---- epilogue: next-stage x (f16) -> X @264 cg<16; C -> Y --------
#pragma unroll
        for (int fm = 0; fm < 2; ++fm)
#pragma unroll
            for (int fj = 0; fj < 3; ++fj) {
                int mloc = mwave*32 + fm*16 + (lane>>4)*4;
                int jl   = ncol*48 + fj*16 + (lane & 15);
                floatx4 res;
#pragma unroll
                for (int r = 0; r < 4; ++r) res[r] = acc4[fm][fj][r] + accL4[fm][fj][r] * (1.0f/1024.0f);
                *(uint2*)&X[jl*264 + mloc] = pack_res(acc4[fm][fj], accL4[fm][fj]);
                *(floatx4*)&YC[jl*132 + mloc] = res;
            }
        __syncthreads();

        // ---- pool: sum 32 points per (v, ch) -> replica atomics ----------
        const int rsel = (blockIdx.x & (NM_REP-1)) * NM_STRIDE;
        float* nmS = nm_acc + (size_t)st*NM_BLK;
        if (tid < 384) {
            int v = tid >> 7, ch = tid & 127;
            float sum = 0.f;
#pragma unroll 1
            for (int pt = 0; pt < 32; ++pt) sum += YC[(pt*3+v)*132 + ch];
            atomicAdd(nmS + rsel + (bB*3+v)*128 + ch, sum);
        }
        // Producer ordering WITHOUT cache ops: drain this thread's atomics,
        // then barrier (covers the whole block).
        asm volatile("s_waitcnt vmcnt(0)" ::: "memory");
        __syncthreads();
        if (tid == 0)
            __hip_atomic_fetch_add(&cnt[st*4+bB], 1, __ATOMIC_RELAXED, __HIP_MEMORY_SCOPE_AGENT);
        // NOTE: the wait + pooled-fill for the next stage happens INSIDE
        // the next iteration, after its early-half gemms.
    }

    // ---- folded head: blocks 0..3 compute out[b] -------------------------
    if (blockIdx.x < 4) {
        const int b = blockIdx.x;
        if (tid == 0) {
            while (__hip_atomic_load(&cnt[16+b], __ATOMIC_RELAXED, __HIP_MEMORY_SCOPE_AGENT) < BPB)
                __builtin_amdgcn_s_sleep(8);
        }
        __syncthreads();
        float* xs = (float*)smem_raw;               // [128][3]
        float* ys = xs + 384;
        const float* nm4 = nm_acc + (size_t)4*NM_BLK;
        if (tid < 128) {
            int c = tid;
            float s0 = 0.f, s1 = 0.f, s2 = 0.f;
#pragma unroll
            for (int rep = 0; rep < NM_REP; ++rep) {
                s0 += __hip_atomic_load(nm4 + rep*NM_STRIDE + (b*3+0)*128 + c, __ATOMIC_RELAXED, __HIP_MEMORY_SCOPE_AGENT);
                s1 += __hip_atomic_load(nm4 + rep*NM_STRIDE + (b*3+1)*128 + c, __ATOMIC_RELAXED, __HIP_MEMORY_SCOPE_AGENT);
                s2 += __hip_atomic_load(nm4 + rep*NM_STRIDE + (b*3+2)*128 + c, __ATOMIC_RELAXED, __HIP_MEMORY_SCOPE_AGENT);
            }
            xs[c*3+0] = s0 * (1.0f/2048.0f);
            xs[c*3+1] = s1 * (1.0f/2048.0f);
            xs[c*3+2] = s2 * (1.0f/2048.0f);
        }
        __syncthreads();
        if (tid < 128) {
            int c = tid;
            float d0 = 0.f, d1 = 0.f, d2 = 0.f;
            for (int i = 0; i < 128; ++i) {
                float w = act_d[c*128 + i];
                d0 = fmaf(w, xs[i*3+0], d0);
                d1 = fmaf(w, xs[i*3+1], d1);
                d2 = fmaf(w, xs[i*3+2], d2);
            }
            float x0 = xs[c*3+0], x1 = xs[c*3+1], x2 = xs[c*3+2];
            float dot = x0*d0 + x1*d1 + x2*d2;
            float y0, y1, y2;
            if (dot >= 0.f) { y0 = x0; y1 = x1; y2 = x2; }
            else {
                float dsq = d0*d0 + d1*d1 + d2*d2 + 1e-8f;
                float sc = dot / dsq;
                y0 = x0 - sc*d0; y1 = x1 - sc*d1; y2 = x2 - sc*d2;
            }
            ys[c*3+0] = y0; ys[c*3+1] = y1; ys[c*3+2] = y2;
        }
        __syncthreads();
        if (tid < 128) {
            int c = tid;
            float o0 = 0.f, o1 = 0.f, o2 = 0.f;
            for (int i = 0; i < 128; ++i) {
                float w = fc_c[c*128 + i];
                o0 = fmaf(w, ys[i*3+0], o0);
                o1 = fmaf(w, ys[i*3+1], o1);
                o2 = fmaf(w, ys[i*3+2], o2);
            }
            out[b*384 + c*3 + 0] = o0;
            out[b*384 + c*3 + 1] = o1;
            out[b*384 + c*3 + 2] = o2;
        }
    }
}

// ---------------------------------------------------------------------------
extern "C" void kernel_launch(void* const* d_in, const int* in_sizes, int n_in,
                              void* d_out, int out_size, void* d_ws, size_t ws_size,
                              hipStream_t stream)
{
    const float* p      = (const float*)d_in[0];
    const float* fc_pos = (const float*)d_in[1];
    const float* bd0    = (const float*)d_in[2];
    const float* bW0    = (const float*)d_in[3];
    const float* bd1    = (const float*)d_in[4];
    const float* bW1    = (const float*)d_in[5];
    const float* bWs    = (const float*)d_in[6];
    const float* fc_c   = (const float*)d_in[7];
    const float* act_d  = (const float*)d_in[8];
    float* out = (float*)d_out;

    // Workspace layout (16B-aligned)
    char* w = (char*)d_ws;
    float* m_buf  = (float*)w;  w += 98304;                  // knn means
    float* nm_acc = (float*)w;  w += (size_t)5*NM_BLK*4;     // replicated pool sums
    int*   cnt    = (int*)w;    w += 128;                    // arrival counters (zeroed w/ nm)
    u16*   Wswz   = (u16*)w;    w += (size_t)2*WTOT*2;       // swizzled split weights

    static bool attr_set = false;
    if (!attr_set) {
        hipFuncSetAttribute((const void*)resnet_kernel,
                            hipFuncAttributeMaxDynamicSharedMemorySize, LDS_BYTES);
        attr_set = true;
    }

    prep_kernel<<<dim3(1024 + 3200), dim3(256), 0, stream>>>(
        p, m_buf, bd0, bW0, bd1, bW1, bWs, Wswz, nm_acc);

    resnet_kernel<<<dim3(NBLK), dim3(512), LDS_BYTES, stream>>>(
        Wswz, p, m_buf, fc_pos, nm_acc, cnt, act_d, fc_c, out);

    (void)in_sizes; (void)n_in; (void)out_size; (void)ws_size;
}